// Round 18
// baseline (116.333 us; speedup 1.0000x reference)
//
#include <hip/hip_runtime.h>
#include <hip/hip_bf16.h>

constexpr int EMBED = 1024;
constexpr int NHEAD = 16;
constexpr int HDIM  = 64;
constexpr int BATCH = 2;
constexpr int SEQ   = 2048;
constexpr int MROWS = BATCH * SEQ;   // 4096
constexpr int NKB   = EMBED / 32;    // 32 k-blocks of 32
constexpr int NT    = SEQ / 64;      // 32 KV tiles

typedef __attribute__((ext_vector_type(8)))  short          bf8;
typedef __attribute__((ext_vector_type(8)))  unsigned short us8;
typedef __attribute__((ext_vector_type(16))) float          f32x16;
typedef __attribute__((ext_vector_type(2)))  int            i32x2;

__device__ __forceinline__ unsigned short f2bf(float f) {  // RNE fp32->bf16
  unsigned u = __float_as_uint(f);
  u += 0x7fffu + ((u >> 16) & 1u);
  return (unsigned short)(u >> 16);
}
__device__ __forceinline__ void async16(const void* g, void* l) {
  __builtin_amdgcn_global_load_lds(
      (const __attribute__((address_space(1))) unsigned int*)g,
      (__attribute__((address_space(3))) unsigned int*)l, 16, 0, 0);
}
__device__ __forceinline__ i32x2 swap32(int a, int b) {
  return __builtin_amdgcn_permlane32_swap(a, b, false, false);
}
__device__ __forceinline__ unsigned cvt2(float a, float b) {
  union { __hip_bfloat162 bb; unsigned u; } cv;
  cv.bb = __float22bfloat162_rn(float2{a, b});
  return cv.u;
}
__device__ __forceinline__ void bar_pre() {
  __builtin_amdgcn_s_barrier();
  __builtin_amdgcn_sched_barrier(0);
}
__device__ __forceinline__ void bar_post() {
  __builtin_amdgcn_sched_barrier(0);
  __builtin_amdgcn_s_barrier();
}

// ---------------------------------------------------------------------------
// Fused pack kernel (unchanged from round 16/17).
// ---------------------------------------------------------------------------
__global__ __launch_bounds__(256) void pack_all2_k(
    const float* __restrict__ x,
    const float* __restrict__ W0, const float* __restrict__ W1,
    const float* __restrict__ W2, const float* __restrict__ W3,
    char* __restrict__ Xp, char* __restrict__ Wpk)
{
  __shared__ float LDSf[8 * 1032];
  const int blk = blockIdx.x;
  const int tid = threadIdx.x;
  if (blk < 2048) {
    int sid = blk * 256 + tid;
    int s = sid & 7, t = (sid >> 3) & 31, u = sid >> 8;
    int c = s ^ (u & 7);
    int par = c >> 2, kq = c & 3;
    const float* src = x + (size_t)(2 * u + par) * EMBED + t * 32 + kq * 8;
    us8 o;
    #pragma unroll
    for (int e = 0; e < 8; ++e) o[e] = f2bf(src[e]);
    *(us8*)(Xp + ((size_t)sid << 4)) = o;
  } else {
    const int bb = blk - 2048;
    const int y = bb >> 7, r = bb & 127, t = r >> 2, q = r & 3;
    const float* W = (y == 0) ? W0 : (y == 1) ? W1 : (y == 2) ? W2 : W3;
    char* op = Wpk + ((size_t)y << 21);
    #pragma unroll
    for (int it = 0; it < 8; ++it) {
      int f4 = it * 256 + tid;
      int row = f4 >> 8, col4 = (f4 & 255) << 2;
      float4 v = *(const float4*)(W + (size_t)(t * 32 + q * 8 + row) * EMBED + col4);
      *(float4*)(&LDSf[row * 1032 + col4]) = v;
    }
    __syncthreads();
    #pragma unroll
    for (int it = 0; it < 4; ++it) {
      int sid2 = it * 256 + tid;
      int u = sid2 >> 1, par = sid2 & 1;
      int s = ((par << 2) | q) ^ (u & 7);
      us8 o;
      #pragma unroll
      for (int e = 0; e < 8; ++e) o[e] = f2bf(LDSf[e * 1032 + 2 * u + par]);
      *(us8*)(op + (((size_t)(u << 8) + (t << 3) + s) << 4)) = o;
    }
  }
}

// ---------------------------------------------------------------------------
// FUSED QKV GEMM, M64 x N128, A-operand DIRECT global->reg (Xp layout ==
// fragment layout; panel is L2-hot across the 8 cb blocks). W staged via
// async16 into 2x24KB LDS dbuf. Pipelined: W(t+1) async16 + a(t+1) global
// loads issued, then vmcnt(10) (= the 10 just-issued stay in flight).
// LDS per block-step: write 24KB + read 24KB (was 28+40).
// ---------------------------------------------------------------------------
__global__ __launch_bounds__(256) void gemm_qkv_fused_k(
    const char* __restrict__ Apk, const char* __restrict__ Wpk,
    const float* __restrict__ B0, const float* __restrict__ B1, const float* __restrict__ B2,
    unsigned short* __restrict__ Qbf, unsigned short* __restrict__ Kbf,
    unsigned short* __restrict__ Vt)
{
  __shared__ __align__(16) char Wsm[49152];   // 2 bufs x (3z x 8KB)

  const int tid  = threadIdx.x;
  const int lane = tid & 63;
  const int wid  = tid >> 6;
  const int ln31 = lane & 31, lhalf = lane >> 5;

  const int bid = blockIdx.x;                 // 512
  const int swz = (bid & 7) * 64 + (bid >> 3);
  const int rp  = swz >> 3, cb = swz & 7;

  const int M0 = rp * 64, N0 = cb * 128;
  const int U0 = rp * 32, V0 = cb * 64;

  // W staging addresses (6 async16/thread: 3z x 2)
  const char* wb[2]; int lw[2];
  #pragma unroll
  for (int i = 0; i < 2; ++i) {
    int idx = i * 256 + tid;
    wb[i] = Wpk + ((size_t)(V0 + (idx >> 3)) << 12) + ((idx & 7) << 4);
    lw[i] = i * 4096 + tid * 16;
  }

  // A fragment base pointers (lane-constant; + t*128 per step)
  const char* bA[2][2];
  #pragma unroll
  for (int mi = 0; mi < 2; ++mi)
    #pragma unroll
    for (int kb = 0; kb < 2; ++kb) {
      int m = mi * 32 + ln31;
      int u = m >> 1;
      int kq = (kb << 1) | lhalf;
      int s = (((m & 1) << 2) | kq) ^ (u & 7);
      bA[mi][kb] = Apk + ((size_t)(U0 + u) << 12) + (s << 4);
    }

  f32x16 acc[3][2];
  #pragma unroll
  for (int z = 0; z < 3; ++z)
    #pragma unroll
    for (int mi = 0; mi < 2; ++mi)
      #pragma unroll
      for (int q = 0; q < 16; ++q) acc[z][mi][q] = 0.f;

  bf8 aR[2][2], aS[2][2];

  // prologue: W(0) -> buf0, a(0) -> aR
  #pragma unroll
  for (int z = 0; z < 3; ++z)
    #pragma unroll
    for (int i = 0; i < 2; ++i)
      async16(wb[i] + ((size_t)z << 21), Wsm + z * 8192 + lw[i]);
  #pragma unroll
  for (int mi = 0; mi < 2; ++mi)
    #pragma unroll
    for (int kb = 0; kb < 2; ++kb)
      aR[mi][kb] = *(const bf8*)(bA[mi][kb]);

#define QKV_BODY(T, AUSE, ALOAD)                                               \
  {                                                                            \
    const int c = (T) & 1;                                                     \
    if ((T) + 1 < NKB) {                                                       \
      const int off = ((T) + 1) << 7;                                          \
      _Pragma("unroll")                                                        \
      for (int z = 0; z < 3; ++z)                                              \
        _Pragma("unroll")                                                      \
        for (int i = 0; i < 2; ++i)                                            \
          async16(wb[i] + ((size_t)z << 21) + off,                             \
                  Wsm + (c ^ 1) * 24576 + z * 8192 + lw[i]);                   \
      _Pragma("unroll")                                                        \
      for (int mi = 0; mi < 2; ++mi)                                           \
        _Pragma("unroll")                                                      \
        for (int kb = 0; kb < 2; ++kb)                                         \
          ALOAD[mi][kb] = *(const bf8*)(bA[mi][kb] + off);                     \
      asm volatile("s_waitcnt vmcnt(10)" ::: "memory");                        \
    } else {                                                                   \
      asm volatile("s_waitcnt vmcnt(0)" ::: "memory");                         \
    }                                                                          \
    bar_pre();                                                                 \
    const char* Wb = Wsm + c * 24576;                                          \
    _Pragma("unroll")                                                          \
    for (int kb = 0; kb < 2; ++kb) {                                           \
      const int kq = (kb << 1) | lhalf;                                        \
      const int n = wid * 32 + ln31;                                           \
      const int un = n >> 1;                                                   \
      const int sn = (((n & 1) << 2) | kq) ^ (un & 7);                         \
      _Pragma("unroll")                                                        \
      for (int z = 0; z < 3; ++z) {                                            \
        bf8 b = *(const bf8*)(Wb + z * 8192 + un * 128 + sn * 16);             \
        acc[z][0] = __builtin_amdgcn_mfma_f32_32x32x16_bf16(                   \
            AUSE[0][kb], b, acc[z][0], 0, 0, 0);                               \
        acc[z][1] = __builtin_amdgcn_mfma_f32_32x32x16_bf16(                   \
            AUSE[1][kb], b, acc[z][1], 0, 0, 0);                               \
      }                                                                        \
    }                                                                          \
    bar_post();                                                                \
  }

  for (int t = 0; t < NKB; t += 2) {
    QKV_BODY(t,     aR, aS)
    QKV_BODY(t + 1, aS, aR)
  }
#undef QKV_BODY

  // epilogues (unchanged from round 16/17)
  const int col = N0 + wid * 32 + ln31;
  #pragma unroll
  for (int z = 0; z < 2; ++z) {
    unsigned short* Cb = (z == 0) ? Qbf : Kbf;
    const float* Bv = (z == 0) ? B0 : B1;
    const float sc = (z == 0) ? (1.44269504088896f / 64.0f) : 1.0f;
    float bb = Bv[col];
    #pragma unroll
    for (int mi = 0; mi < 2; ++mi)
      #pragma unroll
      for (int r = 0; r < 16; ++r) {
        int row = M0 + mi * 32 + (r & 3) + ((r >> 2) << 3) + (lhalf << 2);
        Cb[(size_t)row * EMBED + col] = f2bf((acc[z][mi][r] + bb) * sc);
      }
  }
  {
    const int tile = (M0 & 2047) >> 6;
    const int bb   = M0 >> 11;
    const int hh = col >> 6, dl = col & 63;
    const float bv = B2[col];
    size_t base2 = (((size_t)(bb * 16 + hh)) << 17) + ((size_t)tile << 12) + (dl << 6);
    unsigned pkq[2][4][2];
    #pragma unroll
    for (int mi = 0; mi < 2; ++mi)
      #pragma unroll
      for (int rg = 0; rg < 4; ++rg) {
        pkq[mi][rg][0] = cvt2(acc[2][mi][4 * rg + 0] + bv, acc[2][mi][4 * rg + 1] + bv);
        pkq[mi][rg][1] = cvt2(acc[2][mi][4 * rg + 2] + bv, acc[2][mi][4 * rg + 3] + bv);
      }
    #pragma unroll
    for (int gk = 0; gk < 8; ++gk) {
      const int mi = gk >> 2, rg = gk & 3;
      i32x2 e0 = swap32((int)pkq[mi][rg][0], (int)pkq[mi][rg][0]);
      i32x2 e1 = swap32((int)pkq[mi][rg][1], (int)pkq[mi][rg][1]);
      int g = gk ^ (dl & 7);
      if ((g >> 2) == lhalf) {
        union { unsigned u[4]; us8 v; } o;
        o.u[0] = (unsigned)e0[0]; o.u[1] = (unsigned)e1[0];
        o.u[2] = (unsigned)e0[1]; o.u[3] = (unsigned)e1[1];
        *(us8*)(Vt + base2 + (g << 3)) = o.v;
      }
    }
  }
}

// ---------------------------------------------------------------------------
// Output projection, plain bf16, M64 x N128, BK=64 (round-16 form, unchanged).
// ---------------------------------------------------------------------------
__global__ __launch_bounds__(256) void gemm_out_bf16_k(
    const char* __restrict__ Apk, const char* __restrict__ Wpk,
    const float* __restrict__ Bv, float* __restrict__ Cf)
{
  __shared__ __align__(16) char lds[49152];

  const int tid  = threadIdx.x;
  const int lane = tid & 63;
  const int wid  = tid >> 6;
  const int ln31 = lane & 31, lhalf = lane >> 5;

  const int bid = blockIdx.x;
  const int swz = (bid & 7) * 64 + (bid >> 3);
  const int rp  = swz >> 3, cb = swz & 7;

  const int M0 = rp * 64, N0 = cb * 128;
  const int U0 = rp * 32, V0 = cb * 64;

  const char* ab[2]; int la[2];
  #pragma unroll
  for (int i = 0; i < 2; ++i) {
    int idx = i * 256 + tid;
    int ul = idx >> 4, tt = (idx >> 3) & 1, sl = idx & 7;
    ab[i] = Apk + ((size_t)(U0 + ul) << 12) + (tt << 7) + (sl << 4);
    la[i] = i * 4096 + tid * 16;
  }
  const char* wb[4]; int lw[4];
  #pragma unroll
  for (int j = 0; j < 4; ++j) {
    int idx = j * 256 + tid;
    int ul = idx >> 4, tt = (idx >> 3) & 1, sl = idx & 7;
    wb[j] = Wpk + ((size_t)(V0 + ul) << 12) + (tt << 7) + (sl << 4);
    lw[j] = 8192 + j * 4096 + tid * 16;
  }

  f32x16 acc[2];
  #pragma unroll
  for (int mi = 0; mi < 2; ++mi)
    #pragma unroll
    for (int q = 0; q < 16; ++q) acc[mi][q] = 0.f;

  #pragma unroll
  for (int i = 0; i < 2; ++i) async16(ab[i], lds + la[i]);
  #pragma unroll
  for (int j = 0; j < 4; ++j) async16(wb[j], lds + lw[j]);

  for (int T = 0; T < NKB / 2; ++T) {
    const int c = T & 1;
    if (T + 1 < NKB / 2) {
      const int off = (T + 1) << 8;
      #pragma unroll
      for (int i = 0; i < 2; ++i) async16(ab[i] + off, lds + (c ^ 1) * 24576 + la[i]);
      #pragma unroll
      for (int j = 0; j < 4; ++j) async16(wb[j] + off, lds + (c ^ 1) * 24576 + lw[j]);
      asm volatile("s_waitcnt vmcnt(6)" ::: "memory");
    } else {
      asm volatile("s_waitcnt vmcnt(0)" ::: "memory");
    }
    bar_pre();
    const char* Ab = lds + c * 24576;
    const char* Wb = Ab + 8192;
    #pragma unroll
    for (int tt = 0; tt < 2; ++tt) {
      #pragma unroll
      for (int kb = 0; kb < 2; ++kb) {
        const int kq = (kb << 1) | lhalf;
        bf8 a[2];
        #pragma unroll
        for (int mi = 0; mi < 2; ++mi) {
          int m = mi * 32 + ln31;
          int u = m >> 1;
          int s = (((m & 1) << 2) | kq) ^ (u & 7);
          a[mi] = *(const bf8*)(Ab + u * 256 + tt * 128 + s * 16);
        }
        const int n = wid * 32 + ln31;
        const int un = n >> 1;
        const int sn = (((n & 1) << 2) | kq) ^ (un & 7);
        bf8 b = *(const bf8*)(Wb + un * 256 + tt * 128 + sn * 16);
        acc[0] = __builtin_amdgcn_mfma_f32_32x32x16_bf16(a[0], b, acc[0], 0, 0, 0);
        acc[1] = __builtin_amdgcn_mfma_f32_32x32x16_bf16(a[1], b, acc[1], 0, 0, 0);
      }
    }
    bar_post();
  }

  const int col = N0 + wid * 32 + ln31;
  const float bb = Bv[col];
  #pragma unroll
  for (int mi = 0; mi < 2; ++mi)
    #pragma unroll
    for (int r = 0; r < 16; ++r) {
      int row = M0 + mi * 32 + (r & 3) + ((r >> 2) << 3) + (lhalf << 2);
      Cf[(size_t)row * EMBED + col] = acc[mi][r] + bb;
    }
}

// ---------------------------------------------------------------------------
// MFMA flash attention (round-17 form, unchanged).
// ---------------------------------------------------------------------------
__global__ __launch_bounds__(512) void attn_mfma_k(
    const unsigned short* __restrict__ Qb, const unsigned short* __restrict__ Kb,
    const char* __restrict__ Vt, char* __restrict__ A2)
{
  __shared__ __align__(16) char lds[32768];

  const int bid = blockIdx.x;
  const int swz = (bid & 7) * 32 + (bid >> 3);
  const int qt = swz & 7, h = (swz >> 3) & 15, b = swz >> 7;

  const int tid  = threadIdx.x;
  const int lane = tid & 63;
  const int qw   = tid >> 6;
  const int ln31 = lane & 31, lh = lane >> 5;
  const int l7   = ln31 & 7;

  const int q0 = qt * 256;

  bf8 qf[4];
  {
    const size_t qoff = (size_t)(b * SEQ + q0 + qw * 32 + ln31) * EMBED + h * HDIM;
    #pragma unroll
    for (int kd = 0; kd < 4; ++kd)
      qf[kd] = *(const bf8*)(Qb + qoff + (2 * kd + lh) * 8);
  }

  const unsigned short* ksrc;
  {
    int r = tid >> 3, s7 = tid & 7;
    int un = s7 ^ (r & 7);
    ksrc = Kb + (size_t)(b * SEQ + r) * EMBED + h * HDIM + un * 8;
  }
  const char* vtb = Vt + ((size_t)(b * 16 + h) << 18);
  const int lk = tid * 16;

  async16(ksrc, lds + lk);
  async16(vtb + lk, lds + 8192 + lk);

  const bf8 ones = {0x3F80, 0x3F80, 0x3F80, 0x3F80, 0x3F80, 0x3F80, 0x3F80, 0x3F80};
  f32x16 z16;
  #pragma unroll
  for (int r = 0; r < 16; ++r) z16[r] = 0.f;

  f32x16 oacc[2], oacc3;
  #pragma unroll
  for (int df = 0; df < 2; ++df)
    #pragma unroll
    for (int r = 0; r < 16; ++r) oacc[df][r] = 0.f;
  oacc3 = z16;

  for (int t = 0; t < NT; ++t) {
    const int c = t & 1;
    if (t + 1 < NT) {
      async16(ksrc + (size_t)((t + 1) * 64) * EMBED, lds + (c ^ 1) * 16384 + lk);
      async16(vtb + ((t + 1) << 13) + lk, lds + (c ^ 1) * 16384 + 8192 + lk);
      asm volatile("s_waitcnt vmcnt(2)" ::: "memory");
    } else {
      asm volatile("s_waitcnt vmcnt(0)" ::: "memory");
    }
    bar_pre();
    const char* Kbuf = lds + c * 16384;
    const char* Vbuf = Kbuf + 8192;

    f32x16 sacc[2];
    __builtin_amdgcn_s_setprio(1);
    #pragma unroll
    for (int kf = 0; kf < 2; ++kf) {
      bf8 ka0 = *(const bf8*)(Kbuf + (32 * kf + ln31) * 128 + ((lh ^ l7) << 4));
      sacc[kf] = __builtin_amdgcn_mfma_f32_32x32x16_bf16(ka0, qf[0], z16, 0, 0, 0);
      #pragma unroll
      for (int kd = 1; kd < 4; ++kd) {
        bf8 ka = *(const bf8*)(Kbuf + (32 * kf + ln31) * 128 + (((2 * kd + lh) ^ l7) << 4));
        sacc[kf] = __builtin_amdgcn_mfma_f32_32x32x16_bf16(ka, qf[kd], sacc[kf], 0, 0, 0);
      }
    }
    __builtin_amdgcn_s_setprio(0);

    unsigned pk[2][8];
    #pragma unroll
    for (int g = 0; g < 4; ++g)
      #pragma unroll
      for (int j = 0; j < 2; ++j)
        pk[0][2 * g + j] = cvt2(__builtin_amdgcn_exp2f(sacc[0][4 * g + 2 * j]),
                                __builtin_amdgcn_exp2f(sacc[0][4 * g + 2 * j + 1]));
    __builtin_amdgcn_s_setprio(1);
    #pragma unroll
    for (int kb = 0; kb < 2; ++kb) {
      const int b4 = (kb & 1) * 4;
      i32x2 r02 = swap32((int)pk[0][b4 + 0], (int)pk[0][b4 + 2]);
      i32x2 r13 = swap32((int)pk[0][b4 + 1], (int)pk[0][b4 + 3]);
      union { unsigned u[4]; bf8 v; } pf;
      pf.u[0] = (unsigned)r02[0]; pf.u[1] = (unsigned)r13[0];
      pf.u[2] = (unsigned)r02[1]; pf.u[3] = (unsigned)r13[1];
      #pragma unroll
      for (int df = 0; df < 2; ++df) {
        bf8 va = *(const bf8*)(Vbuf + (32 * df + ln31) * 128 + (((2 * kb + lh) ^ l7) << 4));
        oacc[df] = __builtin_amdgcn_mfma_f32_32x32x16_bf16(va, pf.v, oacc[df], 0, 0, 0);
      }
      oacc3 = __builtin_amdgcn_mfma_f32_32x32x16_bf16(ones, pf.v, oacc3, 0, 0, 0);
    }
    __builtin_amdgcn_s_setprio(0);
    #pragma unroll
    for (int g = 0; g < 4; ++g)
      #pragma unroll
      for (int j = 0; j < 2; ++j)
        pk[1][2 * g + j] = cvt2(__builtin_amdgcn_exp2f(sacc[1][4 * g + 2 * j]),
                                __builtin_amdgcn_exp2f(sacc[1][4 * g + 2 * j + 1]));
    __builtin_amdgcn_s_setprio(1);
    #pragma unroll
    for (int kb = 2; kb < 4; ++kb) {
      const int b4 = (kb & 1) * 4;
      i32x2 r02 = swap32((int)pk[1][b4 + 0], (int)pk[1][b4 + 2]);
      i32x2 r13 = swap32((int)pk[1][b4 + 1], (int)pk[1][b4 + 3]);
      union { unsigned u[4]; bf8 v; } pf;
      pf.u[0] = (unsigned)r02[0]; pf.u[1] = (unsigned)r13[0];
      pf.u[2] = (unsigned)r02[1]; pf.u[3] = (unsigned)r13[1];
      #pragma unroll
      for (int df = 0; df < 2; ++df) {
        bf8 va = *(const bf8*)(Vbuf + (32 * df + ln31) * 128 + (((2 * kb + lh) ^ l7) << 4));
        oacc[df] = __builtin_amdgcn_mfma_f32_32x32x16_bf16(va, pf.v, oacc[df], 0, 0, 0);
      }
      oacc3 = __builtin_amdgcn_mfma_f32_32x32x16_bf16(ones, pf.v, oacc3, 0, 0, 0);
    }
    __builtin_amdgcn_s_setprio(0);
    bar_post();
  }

  const float inv = 1.0f / oacc3[0];
  float fl[8][4], fh[8][4];
  #pragma unroll
  for (int df = 0; df < 2; ++df)
    #pragma unroll
    for (int r = 0; r < 16; ++r) {
      float o = oacc[df][r] * inv;
      i32x2 rr = swap32(__float_as_int(o), __float_as_int(o));
      fl[df * 4 + (r >> 2)][r & 3] = __int_as_float(rr[0]);
      fh[df * 4 + (r >> 2)][r & 3] = __int_as_float(rr[1]);
    }

  const int row = b * SEQ + q0 + qw * 32 + ln31;
  const int u = row >> 1, par = row & 1;
  #pragma unroll
  for (int g = 0; g < 8; ++g) {
    us8 hi;
    #pragma unroll
    for (int e = 0; e < 8; ++e) {
      float f = (e < 4) ? fl[g][e] : fh[g][e - 4];
      hi[e] = f2bf(f);
    }
    int t_blk = 2 * h + (g >> 2), kq = g & 3;
    size_t ub = ((size_t)(u * 32 + t_blk)) << 7;
    int s = ((par << 2) | kq) ^ (u & 7);
    *(us8*)(A2 + ub + (s << 4)) = hi;
  }
}

// ---------------------------------------------------------------------------
extern "C" void kernel_launch(void* const* d_in, const int* in_sizes, int n_in,
                              void* d_out, int out_size, void* d_ws, size_t ws_size,
                              hipStream_t stream)
{
  const float* x  = (const float*)d_in[0];
  const float* Wq = (const float*)d_in[1];
  const float* bq = (const float*)d_in[2];
  const float* Wk = (const float*)d_in[3];
  const float* bk = (const float*)d_in[4];
  const float* Wv = (const float*)d_in[5];
  const float* bv = (const float*)d_in[6];
  const float* Wo = (const float*)d_in[7];
  const float* bo = (const float*)d_in[8];
  float* out = (float*)d_out;

  char* wsb = (char*)d_ws;
  char*           Xp  = wsb;                                         // 8MB
  char*           Wpk = wsb + ((size_t)8  << 20);                    // 8MB (4 x 2MB)
  unsigned short* Qbf = (unsigned short*)(wsb + ((size_t)16 << 20)); // 8MB
  unsigned short* Kbf = (unsigned short*)(wsb + ((size_t)24 << 20)); // 8MB
  unsigned short* Vtp = (unsigned short*)(wsb + ((size_t)32 << 20)); // 8MB (V^T image)
  char*           A2  = wsb + ((size_t)40 << 20);                    // 8MB (bf16)

  pack_all2_k<<<dim3(2560), dim3(256), 0, stream>>>(
      x, Wq, Wk, Wv, Wo, Xp, Wpk);

  gemm_qkv_fused_k<<<dim3(512), dim3(256), 0, stream>>>(
      Xp, Wpk, bq, bk, bv, Qbf, Kbf, Vtp);

  attn_mfma_k<<<dim3(256), dim3(512), 0, stream>>>(
      Qbf, Kbf, (const char*)Vtp, A2);

  gemm_out_bf16_k<<<dim3(512), dim3(256), 0, stream>>>(
      A2, Wpk + ((size_t)3 << 21), bo, out);
}

// Round 19
// 110.156 us; speedup vs baseline: 1.0561x; 1.0561x over previous
//
#include <hip/hip_runtime.h>
#include <hip/hip_bf16.h>

constexpr int EMBED = 1024;
constexpr int NHEAD = 16;
constexpr int HDIM  = 64;
constexpr int BATCH = 2;
constexpr int SEQ   = 2048;
constexpr int MROWS = BATCH * SEQ;   // 4096
constexpr int NKB   = EMBED / 32;    // 32 k-blocks of 32
constexpr int NT    = SEQ / 64;      // 32 KV tiles

typedef __attribute__((ext_vector_type(8)))  short          bf8;
typedef __attribute__((ext_vector_type(8)))  unsigned short us8;
typedef __attribute__((ext_vector_type(16))) float          f32x16;
typedef __attribute__((ext_vector_type(2)))  int            i32x2;

__device__ __forceinline__ unsigned short f2bf(float f) {  // RNE fp32->bf16
  unsigned u = __float_as_uint(f);
  u += 0x7fffu + ((u >> 16) & 1u);
  return (unsigned short)(u >> 16);
}
__device__ __forceinline__ void async16(const void* g, void* l) {
  __builtin_amdgcn_global_load_lds(
      (const __attribute__((address_space(1))) unsigned int*)g,
      (__attribute__((address_space(3))) unsigned int*)l, 16, 0, 0);
}
__device__ __forceinline__ i32x2 swap32(int a, int b) {
  return __builtin_amdgcn_permlane32_swap(a, b, false, false);
}
__device__ __forceinline__ unsigned cvt2(float a, float b) {
  union { __hip_bfloat162 bb; unsigned u; } cv;
  cv.bb = __float22bfloat162_rn(float2{a, b});
  return cv.u;
}
__device__ __forceinline__ void bar_pre() {
  __builtin_amdgcn_s_barrier();
  __builtin_amdgcn_sched_barrier(0);
}
__device__ __forceinline__ void bar_post() {
  __builtin_amdgcn_sched_barrier(0);
  __builtin_amdgcn_s_barrier();
}

// ---------------------------------------------------------------------------
// Fused pack kernel: [0,2048) x -> 128B-unit bf16; [2048,2560) W0..W3 via
// coalesced LDS staging (byte-identical output layout).
// ---------------------------------------------------------------------------
__global__ __launch_bounds__(256) void pack_all2_k(
    const float* __restrict__ x,
    const float* __restrict__ W0, const float* __restrict__ W1,
    const float* __restrict__ W2, const float* __restrict__ W3,
    char* __restrict__ Xp, char* __restrict__ Wpk)
{
  __shared__ float LDSf[8 * 1032];
  const int blk = blockIdx.x;
  const int tid = threadIdx.x;
  if (blk < 2048) {
    int sid = blk * 256 + tid;                 // 0..524287
    int s = sid & 7, t = (sid >> 3) & 31, u = sid >> 8;
    int c = s ^ (u & 7);
    int par = c >> 2, kq = c & 3;
    const float* src = x + (size_t)(2 * u + par) * EMBED + t * 32 + kq * 8;
    us8 o;
    #pragma unroll
    for (int e = 0; e < 8; ++e) o[e] = f2bf(src[e]);
    *(us8*)(Xp + ((size_t)sid << 4)) = o;
  } else {
    const int bb = blk - 2048;                 // 0..511
    const int y = bb >> 7, r = bb & 127, t = r >> 2, q = r & 3;
    const float* W = (y == 0) ? W0 : (y == 1) ? W1 : (y == 2) ? W2 : W3;
    char* op = Wpk + ((size_t)y << 21);
    #pragma unroll
    for (int it = 0; it < 8; ++it) {
      int f4 = it * 256 + tid;
      int row = f4 >> 8, col4 = (f4 & 255) << 2;
      float4 v = *(const float4*)(W + (size_t)(t * 32 + q * 8 + row) * EMBED + col4);
      *(float4*)(&LDSf[row * 1032 + col4]) = v;
    }
    __syncthreads();
    #pragma unroll
    for (int it = 0; it < 4; ++it) {
      int sid2 = it * 256 + tid;
      int u = sid2 >> 1, par = sid2 & 1;
      int s = ((par << 2) | q) ^ (u & 7);
      us8 o;
      #pragma unroll
      for (int e = 0; e < 8; ++e) o[e] = f2bf(LDSf[e * 1032 + 2 * u + par]);
      *(us8*)(op + (((size_t)(u << 8) + (t << 3) + s) << 4)) = o;
    }
  }
}

// ---------------------------------------------------------------------------
// FUSED QKV GEMM, M-tile 64 x N 128: grid 512 = 2 blocks/CU.
// Per K-step: stage A 4KB + 3xW 8KB (7 async16/thread), 12 MFMA/wave.
// T4 counted vmcnt(7). LDS 2x28KB.
// z==0: Q scaled log2e/64; z==1: K; z==2: V -> swizzled V^T image.
// ---------------------------------------------------------------------------
__global__ __launch_bounds__(256) void gemm_qkv_fused_k(
    const char* __restrict__ Apk, const char* __restrict__ Wpk,
    const float* __restrict__ B0, const float* __restrict__ B1, const float* __restrict__ B2,
    unsigned short* __restrict__ Qbf, unsigned short* __restrict__ Kbf,
    unsigned short* __restrict__ Vt)
{
  __shared__ __align__(16) char lds[57344];   // 2 x (A 4K | W 3x8K)

  const int tid  = threadIdx.x;
  const int lane = tid & 63;
  const int wid  = tid >> 6;                  // column group 0..3
  const int ln31 = lane & 31, lhalf = lane >> 5;

  const int bid = blockIdx.x;                 // 512
  const int swz = (bid & 7) * 64 + (bid >> 3);
  const int rp  = swz >> 3, cb = swz & 7;     // rp 0..63

  const int M0 = rp * 64, N0 = cb * 128;
  const int U0 = rp * 32, V0 = cb * 64;

  const char* ab = Apk + ((size_t)(U0 + (tid >> 3)) << 12) + ((tid & 7) << 4);
  const int la = tid * 16;                    // wave-uniform base + lane*16
  const char* wb[2]; int lw[2];
  #pragma unroll
  for (int i = 0; i < 2; ++i) {
    int idx = i * 256 + tid;
    wb[i] = Wpk + ((size_t)(V0 + (idx >> 3)) << 12) + ((idx & 7) << 4);
    lw[i] = 4096 + i * 4096 + tid * 16;
  }

  f32x16 acc[3][2];
  #pragma unroll
  for (int z = 0; z < 3; ++z)
    #pragma unroll
    for (int mi = 0; mi < 2; ++mi)
      #pragma unroll
      for (int q = 0; q < 16; ++q) acc[z][mi][q] = 0.f;

  // prologue: tile 0 -> buf 0 (7 async16/thread)
  async16(ab, lds + la);
  #pragma unroll
  for (int z = 0; z < 3; ++z)
    #pragma unroll
    for (int i = 0; i < 2; ++i)
      async16(wb[i] + ((size_t)z << 21), lds + z * 8192 + lw[i]);

  for (int t = 0; t < NKB; ++t) {
    const int c = t & 1;
    if (t + 1 < NKB) {
      const int off = (t + 1) << 7;
      async16(ab + off, lds + (c ^ 1) * 28672 + la);
      #pragma unroll
      for (int z = 0; z < 3; ++z)
        #pragma unroll
        for (int i = 0; i < 2; ++i)
          async16(wb[i] + ((size_t)z << 21) + off,
                  lds + (c ^ 1) * 28672 + z * 8192 + lw[i]);
      asm volatile("s_waitcnt vmcnt(7)" ::: "memory");
    } else {
      asm volatile("s_waitcnt vmcnt(0)" ::: "memory");
    }
    bar_pre();
    const char* Ab = lds + c * 28672;
    const char* Wb = Ab + 4096;
    #pragma unroll
    for (int kb = 0; kb < 2; ++kb) {
      const int kq = (kb << 1) | lhalf;
      bf8 a[2];
      #pragma unroll
      for (int mi = 0; mi < 2; ++mi) {
        int m = mi * 32 + ln31;
        int u = m >> 1;
        int s = (((m & 1) << 2) | kq) ^ (u & 7);
        a[mi] = *(const bf8*)(Ab + u * 128 + s * 16);
      }
      const int n = wid * 32 + ln31;
      const int un = n >> 1;
      const int sn = (((n & 1) << 2) | kq) ^ (un & 7);
      #pragma unroll
      for (int z = 0; z < 3; ++z) {
        bf8 b = *(const bf8*)(Wb + z * 8192 + un * 128 + sn * 16);
        acc[z][0] = __builtin_amdgcn_mfma_f32_32x32x16_bf16(a[0], b, acc[z][0], 0, 0, 0);
        acc[z][1] = __builtin_amdgcn_mfma_f32_32x32x16_bf16(a[1], b, acc[z][1], 0, 0, 0);
      }
    }
    bar_post();
  }

  // epilogues
  const int col = N0 + wid * 32 + ln31;
  #pragma unroll
  for (int z = 0; z < 2; ++z) {
    unsigned short* Cb = (z == 0) ? Qbf : Kbf;
    const float* Bv = (z == 0) ? B0 : B1;
    const float sc = (z == 0) ? (1.44269504088896f / 64.0f) : 1.0f;
    float bb = Bv[col];
    #pragma unroll
    for (int mi = 0; mi < 2; ++mi)
      #pragma unroll
      for (int r = 0; r < 16; ++r) {
        int row = M0 + mi * 32 + (r & 3) + ((r >> 2) << 3) + (lhalf << 2);
        Cb[(size_t)row * EMBED + col] = f2bf((acc[z][mi][r] + bb) * sc);
      }
  }
  {
    const int tile = (M0 & 2047) >> 6;         // M0%64==0: one 64-k tile
    const int bb   = M0 >> 11;
    const int hh = col >> 6, dl = col & 63;
    const float bv = B2[col];
    size_t base2 = (((size_t)(bb * 16 + hh)) << 17) + ((size_t)tile << 12) + (dl << 6);
    unsigned pkq[2][4][2];
    #pragma unroll
    for (int mi = 0; mi < 2; ++mi)
      #pragma unroll
      for (int rg = 0; rg < 4; ++rg) {
        pkq[mi][rg][0] = cvt2(acc[2][mi][4 * rg + 0] + bv, acc[2][mi][4 * rg + 1] + bv);
        pkq[mi][rg][1] = cvt2(acc[2][mi][4 * rg + 2] + bv, acc[2][mi][4 * rg + 3] + bv);
      }
    #pragma unroll
    for (int gk = 0; gk < 8; ++gk) {
      const int mi = gk >> 2, rg = gk & 3;
      i32x2 e0 = swap32((int)pkq[mi][rg][0], (int)pkq[mi][rg][0]);
      i32x2 e1 = swap32((int)pkq[mi][rg][1], (int)pkq[mi][rg][1]);
      int g = gk ^ (dl & 7);
      if ((g >> 2) == lhalf) {
        union { unsigned u[4]; us8 v; } o;
        o.u[0] = (unsigned)e0[0]; o.u[1] = (unsigned)e1[0];
        o.u[2] = (unsigned)e0[1]; o.u[3] = (unsigned)e1[1];
        *(us8*)(Vt + base2 + (g << 3)) = o.v;
      }
    }
  }
}

// ---------------------------------------------------------------------------
// Output projection, plain bf16, M-tile 64 x N 128, BK=64: grid 512,
// LDS 2x24KB, T4 counted vmcnt(6), 8 MFMA/wave-step.
// ---------------------------------------------------------------------------
__global__ __launch_bounds__(256) void gemm_out_bf16_k(
    const char* __restrict__ Apk, const char* __restrict__ Wpk,
    const float* __restrict__ Bv, float* __restrict__ Cf)
{
  __shared__ __align__(16) char lds[49152];   // 2 x (A 8K | W 16K)

  const int tid  = threadIdx.x;
  const int lane = tid & 63;
  const int wid  = tid >> 6;
  const int ln31 = lane & 31, lhalf = lane >> 5;

  const int bid = blockIdx.x;                 // 512
  const int swz = (bid & 7) * 64 + (bid >> 3);
  const int rp  = swz >> 3, cb = swz & 7;

  const int M0 = rp * 64, N0 = cb * 128;
  const int U0 = rp * 32, V0 = cb * 64;

  const char* ab[2]; int la[2];
  #pragma unroll
  for (int i = 0; i < 2; ++i) {
    int idx = i * 256 + tid;
    int ul = idx >> 4, tt = (idx >> 3) & 1, sl = idx & 7;
    ab[i] = Apk + ((size_t)(U0 + ul) << 12) + (tt << 7) + (sl << 4);
    la[i] = i * 4096 + tid * 16;
  }
  const char* wb[4]; int lw[4];
  #pragma unroll
  for (int j = 0; j < 4; ++j) {
    int idx = j * 256 + tid;
    int ul = idx >> 4, tt = (idx >> 3) & 1, sl = idx & 7;
    wb[j] = Wpk + ((size_t)(V0 + ul) << 12) + (tt << 7) + (sl << 4);
    lw[j] = 8192 + j * 4096 + tid * 16;
  }

  f32x16 acc[2];
  #pragma unroll
  for (int mi = 0; mi < 2; ++mi)
    #pragma unroll
    for (int q = 0; q < 16; ++q) acc[mi][q] = 0.f;

  #pragma unroll
  for (int i = 0; i < 2; ++i) async16(ab[i], lds + la[i]);
  #pragma unroll
  for (int j = 0; j < 4; ++j) async16(wb[j], lds + lw[j]);

  for (int T = 0; T < NKB / 2; ++T) {
    const int c = T & 1;
    if (T + 1 < NKB / 2) {
      const int off = (T + 1) << 8;
      #pragma unroll
      for (int i = 0; i < 2; ++i) async16(ab[i] + off, lds + (c ^ 1) * 24576 + la[i]);
      #pragma unroll
      for (int j = 0; j < 4; ++j) async16(wb[j] + off, lds + (c ^ 1) * 24576 + lw[j]);
      asm volatile("s_waitcnt vmcnt(6)" ::: "memory");
    } else {
      asm volatile("s_waitcnt vmcnt(0)" ::: "memory");
    }
    bar_pre();
    const char* Ab = lds + c * 24576;
    const char* Wb = Ab + 8192;
    #pragma unroll
    for (int tt = 0; tt < 2; ++tt) {
      #pragma unroll
      for (int kb = 0; kb < 2; ++kb) {
        const int kq = (kb << 1) | lhalf;
        bf8 a[2];
        #pragma unroll
        for (int mi = 0; mi < 2; ++mi) {
          int m = mi * 32 + ln31;
          int u = m >> 1;
          int s = (((m & 1) << 2) | kq) ^ (u & 7);
          a[mi] = *(const bf8*)(Ab + u * 256 + tt * 128 + s * 16);
        }
        const int n = wid * 32 + ln31;
        const int un = n >> 1;
        const int sn = (((n & 1) << 2) | kq) ^ (un & 7);
        bf8 b = *(const bf8*)(Wb + un * 256 + tt * 128 + sn * 16);
        acc[0] = __builtin_amdgcn_mfma_f32_32x32x16_bf16(a[0], b, acc[0], 0, 0, 0);
        acc[1] = __builtin_amdgcn_mfma_f32_32x32x16_bf16(a[1], b, acc[1], 0, 0, 0);
      }
    }
    bar_post();
  }

  const int col = N0 + wid * 32 + ln31;
  const float bb = Bv[col];
  #pragma unroll
  for (int mi = 0; mi < 2; ++mi)
    #pragma unroll
    for (int r = 0; r < 16; ++r) {
      int row = M0 + mi * 32 + (r & 3) + ((r >> 2) << 3) + (lhalf << 2);
      Cf[(size_t)row * EMBED + col] = acc[mi][r] + bb;
    }
}

// ---------------------------------------------------------------------------
// MFMA flash attention (round-16 proven form): split-K 8-wave, exp2-direct,
// ones-MFMA l, V^T image, T4 counted-vmcnt barriers, interleaved exp/PV.
// ---------------------------------------------------------------------------
__global__ __launch_bounds__(512) void attn_mfma_k(
    const unsigned short* __restrict__ Qb, const unsigned short* __restrict__ Kb,
    const char* __restrict__ Vt, char* __restrict__ A2)
{
  __shared__ __align__(16) char lds[65536];

  const int bid = blockIdx.x;
  const int swz = (bid & 7) * 64 + (bid >> 3);
  const int qt = swz & 15, h = (swz >> 4) & 15, b = swz >> 8;

  const int tid  = threadIdx.x;
  const int kw   = tid >> 8;
  const int tidg = tid & 255;
  const int lane = tid & 63;
  const int qw   = (tid >> 6) & 3;
  const int ln31 = lane & 31, lh = lane >> 5;
  const int l7   = ln31 & 7;

  const int q0 = qt * 128;
  const int sbase = kw * 32768;
  const int T0 = kw * 16;

  bf8 qf[4];
  {
    const size_t qoff = (size_t)(b * SEQ + q0 + qw * 32 + ln31) * EMBED + h * HDIM;
    #pragma unroll
    for (int kd = 0; kd < 4; ++kd)
      qf[kd] = *(const bf8*)(Qb + qoff + (2 * kd + lh) * 8);
  }

  const unsigned short* ksrc[2];
  const char* vtb = Vt + ((size_t)(b * 16 + h) << 18);
  int ldoff[2];
  #pragma unroll
  for (int i = 0; i < 2; ++i) {
    int idx = i * 256 + tidg;
    int r = idx >> 3, s7 = idx & 7;
    int un = s7 ^ (r & 7);
    ksrc[i] = Kb + (size_t)(b * SEQ + r) * EMBED + h * HDIM + un * 8;
    ldoff[i] = i * 4096 + (tidg >> 6) * 1024;
  }

  #pragma unroll
  for (int i = 0; i < 2; ++i) {
    async16(ksrc[i] + (size_t)(T0 * 64) * EMBED, lds + sbase + ldoff[i]);
    async16(vtb + (T0 << 13) + ((i * 256 + tidg) << 4), lds + sbase + 8192 + ldoff[i]);
  }

  const bf8 ones = {0x3F80, 0x3F80, 0x3F80, 0x3F80, 0x3F80, 0x3F80, 0x3F80, 0x3F80};
  f32x16 z16;
  #pragma unroll
  for (int r = 0; r < 16; ++r) z16[r] = 0.f;

  f32x16 oacc[2], oacc3;
  #pragma unroll
  for (int df = 0; df < 2; ++df)
    #pragma unroll
    for (int r = 0; r < 16; ++r) oacc[df][r] = 0.f;
  oacc3 = z16;

  for (int it = 0; it < NT / 2; ++it) {
    const int c = it & 1;
    if (it + 1 < NT / 2) {
      const int tn = T0 + it + 1;
      #pragma unroll
      for (int i = 0; i < 2; ++i) {
        async16(ksrc[i] + (size_t)(tn * 64) * EMBED, lds + sbase + (c ^ 1) * 16384 + ldoff[i]);
        async16(vtb + (tn << 13) + ((i * 256 + tidg) << 4),
                lds + sbase + (c ^ 1) * 16384 + 8192 + ldoff[i]);
      }
      asm volatile("s_waitcnt vmcnt(4)" ::: "memory");
    } else {
      asm volatile("s_waitcnt vmcnt(0)" ::: "memory");
    }
    bar_pre();
    const char* Kbuf = lds + sbase + c * 16384;
    const char* Vbuf = Kbuf + 8192;

    f32x16 sacc[2];
    __builtin_amdgcn_s_setprio(1);
    #pragma unroll
    for (int kf = 0; kf < 2; ++kf) {
      bf8 ka0 = *(const bf8*)(Kbuf + (32 * kf + ln31) * 128 + ((lh ^ l7) << 4));
      sacc[kf] = __builtin_amdgcn_mfma_f32_32x32x16_bf16(ka0, qf[0], z16, 0, 0, 0);
      #pragma unroll
      for (int kd = 1; kd < 4; ++kd) {
        bf8 ka = *(const bf8*)(Kbuf + (32 * kf + ln31) * 128 + (((2 * kd + lh) ^ l7) << 4));
        sacc[kf] = __builtin_amdgcn_mfma_f32_32x32x16_bf16(ka, qf[kd], sacc[kf], 0, 0, 0);
      }
    }
    __builtin_amdgcn_s_setprio(0);

    unsigned pk[2][8];
    #pragma unroll
    for (int g = 0; g < 4; ++g)
      #pragma unroll
      for (int j = 0; j < 2; ++j)
        pk[0][2 * g + j] = cvt2(__builtin_amdgcn_exp2f(sacc[0][4 * g + 2 * j]),
                                __builtin_amdgcn_exp2f(sacc[0][4 * g + 2 * j + 1]));
    __builtin_amdgcn_s_setprio(1);
    #pragma unroll
    for (int kb = 0; kb < 2; ++kb) {
      const int b4 = (kb & 1) * 4;
      i32x2 r02 = swap32((int)pk[0][b4 + 0], (int)pk[0][b4 + 2]);
      i32x2 r13 = swap32((int)pk[0][b4 + 1], (int)pk[0][b4 + 3]);
      union { unsigned u[4]; bf8 v; } pf;
      pf.u[0] = (unsigned)r02[0]; pf.u[1] = (unsigned)r13[0];
      pf.u[2] = (unsigned)r02[1]; pf.u[3] = (unsigned)r13[1];
      #pragma unroll
      for (int df = 0; df < 2; ++df) {
        bf8 va = *(const bf8*)(Vbuf + (32 * df + ln31) * 128 + (((2 * kb + lh) ^ l7) << 4));
        oacc[df] = __builtin_amdgcn_mfma_f32_32x32x16_bf16(va, pf.v, oacc[df], 0, 0, 0);
      }
      oacc3 = __builtin_amdgcn_mfma_f32_32x32x16_bf16(ones, pf.v, oacc3, 0, 0, 0);
    }
    __builtin_amdgcn_s_setprio(0);
    #pragma unroll
    for (int g = 0; g < 4; ++g)
      #pragma unroll
      for (int j = 0; j < 2; ++j)
        pk[1][2 * g + j] = cvt2(__builtin_amdgcn_exp2f(sacc[1][4 * g + 2 * j]),
                                __builtin_amdgcn_exp2f(sacc[1][4 * g + 2 * j + 1]));
    __builtin_amdgcn_s_setprio(1);
    #pragma unroll
    for (int kb = 2; kb < 4; ++kb) {
      const int b4 = (kb & 1) * 4;
      i32x2 r02 = swap32((int)pk[1][b4 + 0], (int)pk[1][b4 + 2]);
      i32x2 r13 = swap32((int)pk[1][b4 + 1], (int)pk[1][b4 + 3]);
      union { unsigned u[4]; bf8 v; } pf;
      pf.u[0] = (unsigned)r02[0]; pf.u[1] = (unsigned)r13[0];
      pf.u[2] = (unsigned)r02[1]; pf.u[3] = (unsigned)r13[1];
      #pragma unroll
      for (int df = 0; df < 2; ++df) {
        bf8 va = *(const bf8*)(Vbuf + (32 * df + ln31) * 128 + (((2 * kb + lh) ^ l7) << 4));
        oacc[df] = __builtin_amdgcn_mfma_f32_32x32x16_bf16(va, pf.v, oacc[df], 0, 0, 0);
      }
      oacc3 = __builtin_amdgcn_mfma_f32_32x32x16_bf16(ones, pf.v, oacc3, 0, 0, 0);
    }
    __builtin_amdgcn_s_setprio(0);
    bar_post();
  }

  // cross-group merge
  float* ex = (float*)lds;
  const int slot = qw * 64 + lane;
  if (kw == 1) {
    #pragma unroll
    for (int df = 0; df < 2; ++df)
      #pragma unroll
      for (int r = 0; r < 16; ++r)
        ex[slot * 34 + df * 16 + r] = oacc[df][r];
    ex[slot * 34 + 32] = oacc3[0];
  }
  __syncthreads();
  if (kw == 1) return;

  #pragma unroll
  for (int df = 0; df < 2; ++df)
    #pragma unroll
    for (int r = 0; r < 16; ++r)
      oacc[df][r] += ex[slot * 34 + df * 16 + r];
  const float ltot = oacc3[0] + ex[slot * 34 + 32];

  const float inv = 1.0f / ltot;
  float fl[8][4], fh[8][4];
  #pragma unroll
  for (int df = 0; df < 2; ++df)
    #pragma unroll
    for (int r = 0; r < 16; ++r) {
      float o = oacc[df][r] * inv;
      i32x2 rr = swap32(__float_as_int(o), __float_as_int(o));
      fl[df * 4 + (r >> 2)][r & 3] = __int_as_float(rr[0]);
      fh[df * 4 + (r >> 2)][r & 3] = __int_as_float(rr[1]);
    }

  const int row = b * SEQ + q0 + qw * 32 + ln31;
  const int u = row >> 1, par = row & 1;
  #pragma unroll
  for (int g = 0; g < 8; ++g) {
    us8 hi;
    #pragma unroll
    for (int e = 0; e < 8; ++e) {
      float f = (e < 4) ? fl[g][e] : fh[g][e - 4];
      hi[e] = f2bf(f);
    }
    int t_blk = 2 * h + (g >> 2), kq = g & 3;
    size_t ub = ((size_t)(u * 32 + t_blk)) << 7;
    int s = ((par << 2) | kq) ^ (u & 7);
    *(us8*)(A2 + ub + (s << 4)) = hi;
  }
}

// ---------------------------------------------------------------------------
extern "C" void kernel_launch(void* const* d_in, const int* in_sizes, int n_in,
                              void* d_out, int out_size, void* d_ws, size_t ws_size,
                              hipStream_t stream)
{
  const float* x  = (const float*)d_in[0];
  const float* Wq = (const float*)d_in[1];
  const float* bq = (const float*)d_in[2];
  const float* Wk = (const float*)d_in[3];
  const float* bk = (const float*)d_in[4];
  const float* Wv = (const float*)d_in[5];
  const float* bv = (const float*)d_in[6];
  const float* Wo = (const float*)d_in[7];
  const float* bo = (const float*)d_in[8];
  float* out = (float*)d_out;

  char* wsb = (char*)d_ws;
  char*           Xp  = wsb;                                         // 8MB
  char*           Wpk = wsb + ((size_t)8  << 20);                    // 8MB (4 x 2MB)
  unsigned short* Qbf = (unsigned short*)(wsb + ((size_t)16 << 20)); // 8MB
  unsigned short* Kbf = (unsigned short*)(wsb + ((size_t)24 << 20)); // 8MB
  unsigned short* Vtp = (unsigned short*)(wsb + ((size_t)32 << 20)); // 8MB (V^T image)
  char*           A2  = wsb + ((size_t)40 << 20);                    // 8MB (bf16)

  pack_all2_k<<<dim3(2560), dim3(256), 0, stream>>>(
      x, Wq, Wk, Wv, Wo, Xp, Wpk);

  gemm_qkv_fused_k<<<dim3(512), dim3(256), 0, stream>>>(
      Xp, Wpk, bq, bk, bv, Qbf, Kbf, Vtp);

  attn_mfma_k<<<dim3(512), dim3(512), 0, stream>>>(
      Qbf, Kbf, (const char*)Vtp, A2);

  gemm_out_bf16_k<<<dim3(512), dim3(256), 0, stream>>>(
      A2, Wpk + ((size_t)3 << 21), bo, out);
}